// Round 2
// baseline (672.957 us; speedup 1.0000x reference)
//
#include <hip/hip_runtime.h>
#include <cstdint>

// Pipeline (all f16 MFMA, fp32 accum, fp32 softmax):
//  1) cast A,B -> f16; transpose-cast W1,W2 -> (N,K) f16
//  2) h = relu(X @ W1 + b1); f = relu(h @ W2 + b2)   [m97-style 128x128x32 MFMA GEMM]
//  3) e = fA @ fB^T (fp32 out, batched), eT = e^T
//  4) row softmax stats (online max/sum) for e and eT
//  5) beta = P(e) @ B, alpha = P(eT) @ A  [softmax applied in A-operand staging]
// Workspace ~189 MB with aliasing (h aliases e region; eT aliases fA/fB; At/Bt alias Af/Bf).
//
// R1 fix: SMAX A-tile staging ran 2 iters (2048 of 4096 values) -> sA rows
// 64..127 uninitialized -> NaN. Now 4 iters.

#define L2E 1.4426950408889634f

typedef _Float16 half8 __attribute__((ext_vector_type(8)));
typedef _Float16 half4v __attribute__((ext_vector_type(4)));
typedef float f32x4 __attribute__((ext_vector_type(4)));

__device__ __forceinline__ void gl_lds16(const void* g, void* l) {
  __builtin_amdgcn_global_load_lds(
      (const __attribute__((address_space(1))) unsigned int*)g,
      (__attribute__((address_space(3))) unsigned int*)l, 16, 0, 0);
}

// C(M,N) = op( X(M,K) @ Y(N,K)^T + bias ),  op = relu if BIASRELU
// SMAX: X-operand generated on the fly as exp(E - rmax)*rinv (row softmax), E fp32 (M,K)
template<int K, bool BIASRELU, bool SMAX, typename OutT>
__global__ __launch_bounds__(256, 2)
void gemm_k(const _Float16* __restrict__ X, const float* __restrict__ E,
            const float* __restrict__ rmax, const float* __restrict__ rinv,
            const _Float16* __restrict__ Y, const float* __restrict__ bias,
            OutT* __restrict__ C, int N, long xbs, long ybs, long cbs)
{
  __shared__ __align__(16) _Float16 sA[128 * 32];
  __shared__ __align__(16) _Float16 sB[128 * 32];
  const int t = threadIdx.x;
  const int lane = t & 63, w = t >> 6;
  const int wr = w >> 1, wc = w & 1;
  const int lm = lane & 15, lk = (lane >> 4) * 8;
  const int m0 = blockIdx.y * 128, n0 = blockIdx.x * 128;
  const int bz = blockIdx.z;
  if constexpr (SMAX) { E += (size_t)bz * xbs; } else { X += (size_t)bz * xbs; }
  Y += (size_t)bz * ybs;
  C += (size_t)bz * cbs;

  f32x4 acc[4][4] = {};

  for (int kt = 0; kt < K; kt += 32) {
    __syncthreads();  // protect LDS vs previous iteration's reads
    if constexpr (SMAX) {
#pragma unroll
      for (int r = 0; r < 4; ++r) {
        int idx = r * 256 + t;
        int row = idx >> 3, c4 = (idx & 7) * 4;
        const float4 v = *(const float4*)(E + (size_t)(m0 + row) * K + kt + c4);
        const float mv = rmax[(size_t)bz * 1024 + m0 + row];
        const float il = rinv[(size_t)bz * 1024 + m0 + row];
        half4v o;
        o[0] = (_Float16)(exp2f((v.x - mv) * L2E) * il);
        o[1] = (_Float16)(exp2f((v.y - mv) * L2E) * il);
        o[2] = (_Float16)(exp2f((v.z - mv) * L2E) * il);
        o[3] = (_Float16)(exp2f((v.w - mv) * L2E) * il);
        *(half4v*)(sA + row * 32 + c4) = o;
      }
    } else {
#pragma unroll
      for (int r = 0; r < 2; ++r) {
        int cid = r * 256 + t;
        int row = cid >> 2, c8 = (cid & 3) * 8;
        gl_lds16(X + (size_t)(m0 + row) * K + kt + c8, sA + cid * 8);
      }
    }
#pragma unroll
    for (int r = 0; r < 2; ++r) {
      int cid = r * 256 + t;
      int row = cid >> 2, c8 = (cid & 3) * 8;
      gl_lds16(Y + (size_t)(n0 + row) * K + kt + c8, sB + cid * 8);
    }
    __syncthreads();  // compiler drains vmcnt before barrier

    half8 af[4], bf[4];
#pragma unroll
    for (int mi = 0; mi < 4; ++mi)
      af[mi] = *(const half8*)(sA + (wr * 64 + mi * 16 + lm) * 32 + lk);
#pragma unroll
    for (int ni = 0; ni < 4; ++ni)
      bf[ni] = *(const half8*)(sB + (wc * 64 + ni * 16 + lm) * 32 + lk);
#pragma unroll
    for (int mi = 0; mi < 4; ++mi)
#pragma unroll
      for (int ni = 0; ni < 4; ++ni)
        acc[mi][ni] = __builtin_amdgcn_mfma_f32_16x16x32_f16(af[mi], bf[ni], acc[mi][ni], 0, 0, 0);
  }

#pragma unroll
  for (int mi = 0; mi < 4; ++mi) {
    const int rbase = m0 + wr * 64 + mi * 16 + (lane >> 4) * 4;
#pragma unroll
    for (int ni = 0; ni < 4; ++ni) {
      const int col = n0 + wc * 64 + ni * 16 + lm;
      float bv = 0.f;
      if constexpr (BIASRELU) bv = bias[col];
#pragma unroll
      for (int q = 0; q < 4; ++q) {
        float v = acc[mi][ni][q] + bv;
        if constexpr (BIASRELU) v = fmaxf(v, 0.f);
        C[(size_t)(rbase + q) * N + col] = (OutT)v;
      }
    }
  }
}

// online row max + 1/sum(exp) — one wave per 1024-float row
__global__ __launch_bounds__(256)
void row_stats(const float* __restrict__ e, float* __restrict__ rmax, float* __restrict__ rinv)
{
  const int row = blockIdx.x * 4 + (threadIdx.x >> 6);
  const int lane = threadIdx.x & 63;
  const float4* p = (const float4*)(e + (size_t)row * 1024);
  float m = -3.0e38f, s = 0.f;
  for (int i = lane; i < 256; i += 64) {
    float4 v = p[i];
    float vv[4] = {v.x, v.y, v.z, v.w};
#pragma unroll
    for (int j = 0; j < 4; ++j) {
      float nm = fmaxf(m, vv[j]);
      s = s * exp2f((m - nm) * L2E) + exp2f((vv[j] - nm) * L2E);
      m = nm;
    }
  }
#pragma unroll
  for (int off = 32; off > 0; off >>= 1) {
    float m2 = __shfl_xor(m, off);
    float s2 = __shfl_xor(s, off);
    float nm = fmaxf(m, m2);
    s = s * exp2f((m - nm) * L2E) + s2 * exp2f((m2 - nm) * L2E);
    m = nm;
  }
  if (lane == 0) { rmax[row] = m; rinv[row] = 1.f / s; }
}

// batched 1024x1024 fp32 transpose
__global__ __launch_bounds__(256)
void transpose_e(const float* __restrict__ in, float* __restrict__ out)
{
  __shared__ float tl[32][33];
  const size_t bo = (size_t)blockIdx.z * 1024 * 1024;
  int x = blockIdx.x * 32 + threadIdx.x;
  int y0 = blockIdx.y * 32;
  for (int i = threadIdx.y; i < 32; i += 8)
    tl[i][threadIdx.x] = in[bo + (size_t)(y0 + i) * 1024 + x];
  __syncthreads();
  int xo = y0 + threadIdx.x;
  int yo0 = blockIdx.x * 32;
  for (int i = threadIdx.y; i < 32; i += 8)
    out[bo + (size_t)(yo0 + i) * 1024 + xo] = tl[threadIdx.x][i];
}

// fp32 (R,C) -> f16 (C,R), batched via blockIdx.z (stride R*C both sides)
__global__ __launch_bounds__(256)
void transpose_cvt(const float* __restrict__ in, _Float16* __restrict__ out, int R, int C)
{
  __shared__ float tl[32][33];
  const size_t bo = (size_t)blockIdx.z * R * C;
  int x = blockIdx.x * 32 + threadIdx.x;
  int y0 = blockIdx.y * 32;
  for (int i = threadIdx.y; i < 32; i += 8)
    tl[i][threadIdx.x] = in[bo + (size_t)(y0 + i) * C + x];
  __syncthreads();
  int xo = y0 + threadIdx.x;
  int c0 = blockIdx.x * 32;
  for (int i = threadIdx.y; i < 32; i += 8)
    out[bo + (size_t)(c0 + i) * R + xo] = (_Float16)tl[threadIdx.x][i];
}

__global__ __launch_bounds__(256)
void cvt_f16(const float* __restrict__ in, _Float16* __restrict__ out, int n4)
{
  int i = blockIdx.x * 256 + threadIdx.x;
  if (i >= n4) return;
  float4 v = ((const float4*)in)[i];
  half4v o;
  o[0] = (_Float16)v.x; o[1] = (_Float16)v.y; o[2] = (_Float16)v.z; o[3] = (_Float16)v.w;
  ((half4v*)out)[i] = o;
}

extern "C" void kernel_launch(void* const* d_in, const int* in_sizes, int n_in,
                              void* d_out, int out_size, void* d_ws, size_t ws_size,
                              hipStream_t stream)
{
  const float* A  = (const float*)d_in[0];
  const float* B  = (const float*)d_in[1];
  const float* W1 = (const float*)d_in[2];
  const float* b1 = (const float*)d_in[3];
  const float* W2 = (const float*)d_in[4];
  const float* b2 = (const float*)d_in[5];
  float* out = (float*)d_out;

  char* ws = (char*)d_ws;
  _Float16* Af  = (_Float16*)(ws + 0);           // 25,165,824 B; later At
  _Float16* Bf  = (_Float16*)(ws + 25165824);    // later Bt
  _Float16* W1t = (_Float16*)(ws + 50331648);    // 1,572,864
  _Float16* W2t = (_Float16*)(ws + 51904512);    // 2,097,152
  _Float16* fA  = (_Float16*)(ws + 54001664);    // 33,554,432
  _Float16* fB  = (_Float16*)(ws + 87556096);    // 33,554,432
  float*    e   = (float*)   (ws + 121110528);   // 67,108,864
  _Float16* h   = (_Float16*)(ws + 121110528);   // alias: h dead before e written
  float*    eT  = (float*)   (ws + 54001664);    // alias fA/fB: written after e-gemm
  float*    me  = (float*)   (ws + 188219392);
  float*    ie  = (float*)   (ws + 188219392 + 65536);
  float*    mt  = (float*)   (ws + 188219392 + 131072);
  float*    it  = (float*)   (ws + 188219392 + 196608);
  _Float16* At = Af;
  _Float16* Bt = Bf;

  dim3 blk(256);
  dim3 tblk(32, 8);

  cvt_f16<<<12288, blk, 0, stream>>>(A, Af, 3145728);
  cvt_f16<<<12288, blk, 0, stream>>>(B, Bf, 3145728);
  transpose_cvt<<<dim3(32, 24, 1), tblk, 0, stream>>>(W1, W1t, 768, 1024);
  transpose_cvt<<<dim3(32, 32, 1), tblk, 0, stream>>>(W2, W2t, 1024, 1024);

  // MLP for A
  gemm_k<768, true, false, _Float16><<<dim3(8, 128, 1), blk, 0, stream>>>(
      Af, nullptr, nullptr, nullptr, W1t, b1, h, 1024, 0, 0, 0);
  gemm_k<1024, true, false, _Float16><<<dim3(8, 128, 1), blk, 0, stream>>>(
      h, nullptr, nullptr, nullptr, W2t, b2, fA, 1024, 0, 0, 0);
  // MLP for B
  gemm_k<768, true, false, _Float16><<<dim3(8, 128, 1), blk, 0, stream>>>(
      Bf, nullptr, nullptr, nullptr, W1t, b1, h, 1024, 0, 0, 0);
  gemm_k<1024, true, false, _Float16><<<dim3(8, 128, 1), blk, 0, stream>>>(
      h, nullptr, nullptr, nullptr, W2t, b2, fB, 1024, 0, 0, 0);

  // e = fA @ fB^T  (batched, fp32 out)
  gemm_k<1024, false, false, float><<<dim3(8, 8, 16), blk, 0, stream>>>(
      fA, nullptr, nullptr, nullptr, fB, nullptr, e, 1024,
      1048576L, 1048576L, 1048576L);

  transpose_e<<<dim3(32, 32, 16), tblk, 0, stream>>>(e, eT);

  row_stats<<<4096, blk, 0, stream>>>(e, me, ie);
  row_stats<<<4096, blk, 0, stream>>>(eT, mt, it);

  // At/Bt (f16, (768,1024) per batch) — overwrite Af/Bf (dead)
  transpose_cvt<<<dim3(24, 32, 16), tblk, 0, stream>>>(A, At, 1024, 768);
  transpose_cvt<<<dim3(24, 32, 16), tblk, 0, stream>>>(B, Bt, 1024, 768);

  // beta = softmax_row(e) @ B   -> out[0 : 12582912]
  gemm_k<1024, false, true, float><<<dim3(6, 8, 16), blk, 0, stream>>>(
      nullptr, e, me, ie, Bt, nullptr, out, 768,
      1048576L, 786432L, 786432L);
  // alpha = softmax_row(eT) @ A -> out[12582912 : ]
  gemm_k<1024, false, true, float><<<dim3(6, 8, 16), blk, 0, stream>>>(
      nullptr, eT, mt, it, At, nullptr, out + 12582912, 768,
      1048576L, 786432L, 786432L);
}

// Round 3
// 648.805 us; speedup vs baseline: 1.0372x; 1.0372x over previous
//
#include <hip/hip_runtime.h>
#include <cstdint>

// R3 restructure:
//  1) cast A,B -> f16 (Af||Bf contiguous = X (32768,768)); transpose-cast W1,W2
//  2) h = relu(X@W1+b1), f = relu(h@W2+b2)  -- single merged gemm per layer
//  3) e = fA @ fB^T (fp32, batched)
//  4) row stats (me,ie); column stats (mc,ic) via partial+combine (no fp32 transpose)
//  5) softmax_apply: read e once -> P (f16 row-softmax) and PT (f16 col-softmax, transposed)
//  6) beta = P @ Bt, alpha = PT @ At  -- plain f16 gemms (global_load_lds path)
// ws layout (max 189,005,824 B):
//  [0]         Af (25165824)      -> later At
//  [25165824]  Bf (25165824)      -> later Bt
//  [50331648]  W1t/W2t (3.7MB)    -> later col-stat partials (512KB)
//  [54001664]  fAB (67108864)     -> later P (33.5MB) + PT (33.5MB)
//  [121110528] h (67108864)       -> later e (67108864)
//  [188219392] me/ie/mc/ic (4x65536)

#define L2E 1.4426950408889634f

typedef _Float16 half8 __attribute__((ext_vector_type(8)));
typedef _Float16 half4v __attribute__((ext_vector_type(4)));
typedef float f32x4 __attribute__((ext_vector_type(4)));

__device__ __forceinline__ void gl_lds16(const void* g, void* l) {
  __builtin_amdgcn_global_load_lds(
      (const __attribute__((address_space(1))) unsigned int*)g,
      (__attribute__((address_space(3))) unsigned int*)l, 16, 0, 0);
}

// C(M,N) = op( X(M,K) @ Y(N,K)^T + bias ),  op = relu if BIASRELU
template<int K, bool BIASRELU, typename OutT>
__global__ __launch_bounds__(256, 2)
void gemm_k(const _Float16* __restrict__ X, const _Float16* __restrict__ Y,
            const float* __restrict__ bias, OutT* __restrict__ C, int N,
            long xbs, long ybs, long cbs)
{
  __shared__ __align__(16) _Float16 sA[128 * 32];
  __shared__ __align__(16) _Float16 sB[128 * 32];
  const int t = threadIdx.x;
  const int lane = t & 63, w = t >> 6;
  const int wr = w >> 1, wc = w & 1;
  const int lm = lane & 15, lk = (lane >> 4) * 8;
  const int m0 = blockIdx.y * 128, n0 = blockIdx.x * 128;
  const int bz = blockIdx.z;
  X += (size_t)bz * xbs;
  Y += (size_t)bz * ybs;
  C += (size_t)bz * cbs;

  f32x4 acc[4][4] = {};

  for (int kt = 0; kt < K; kt += 32) {
    __syncthreads();
#pragma unroll
    for (int r = 0; r < 2; ++r) {
      int cid = r * 256 + t;
      int row = cid >> 2, c8 = (cid & 3) * 8;
      gl_lds16(X + (size_t)(m0 + row) * K + kt + c8, sA + cid * 8);
    }
#pragma unroll
    for (int r = 0; r < 2; ++r) {
      int cid = r * 256 + t;
      int row = cid >> 2, c8 = (cid & 3) * 8;
      gl_lds16(Y + (size_t)(n0 + row) * K + kt + c8, sB + cid * 8);
    }
    __syncthreads();

    half8 af[4], bf[4];
#pragma unroll
    for (int mi = 0; mi < 4; ++mi)
      af[mi] = *(const half8*)(sA + (wr * 64 + mi * 16 + lm) * 32 + lk);
#pragma unroll
    for (int ni = 0; ni < 4; ++ni)
      bf[ni] = *(const half8*)(sB + (wc * 64 + ni * 16 + lm) * 32 + lk);
#pragma unroll
    for (int mi = 0; mi < 4; ++mi)
#pragma unroll
      for (int ni = 0; ni < 4; ++ni)
        acc[mi][ni] = __builtin_amdgcn_mfma_f32_16x16x32_f16(af[mi], bf[ni], acc[mi][ni], 0, 0, 0);
  }

#pragma unroll
  for (int mi = 0; mi < 4; ++mi) {
    const int rbase = m0 + wr * 64 + mi * 16 + (lane >> 4) * 4;
#pragma unroll
    for (int ni = 0; ni < 4; ++ni) {
      const int col = n0 + wc * 64 + ni * 16 + lm;
      float bv = 0.f;
      if constexpr (BIASRELU) bv = bias[col];
#pragma unroll
      for (int q = 0; q < 4; ++q) {
        float v = acc[mi][ni][q] + bv;
        if constexpr (BIASRELU) v = fmaxf(v, 0.f);
        C[(size_t)(rbase + q) * N + col] = (OutT)v;
      }
    }
  }
}

// online row max + 1/sum(exp) — one wave per 1024-float row
__global__ __launch_bounds__(256)
void row_stats(const float* __restrict__ e, float* __restrict__ rmax, float* __restrict__ rinv)
{
  const int row = blockIdx.x * 4 + (threadIdx.x >> 6);
  const int lane = threadIdx.x & 63;
  const float4* p = (const float4*)(e + (size_t)row * 1024);
  float m = -3.0e38f, s = 0.f;
  for (int i = lane; i < 256; i += 64) {
    float4 v = p[i];
    float vv[4] = {v.x, v.y, v.z, v.w};
#pragma unroll
    for (int j = 0; j < 4; ++j) {
      float nm = fmaxf(m, vv[j]);
      s = s * exp2f((m - nm) * L2E) + exp2f((vv[j] - nm) * L2E);
      m = nm;
    }
  }
#pragma unroll
  for (int off = 32; off > 0; off >>= 1) {
    float m2 = __shfl_xor(m, off);
    float s2 = __shfl_xor(s, off);
    float nm = fmaxf(m, m2);
    s = s * exp2f((m - nm) * L2E) + s2 * exp2f((m2 - nm) * L2E);
    m = nm;
  }
  if (lane == 0) { rmax[row] = m; rinv[row] = 1.f / s; }
}

// column-stat partials: block (ry, bz) covers rows ry*256..+255, all 1024 cols.
// thread owns 4 cols (float4). partial layout pm[ry*16+bz][1024].
__global__ __launch_bounds__(256)
void col_partial(const float* __restrict__ e, float* __restrict__ pm, float* __restrict__ ps)
{
  const int ry = blockIdx.x, bz = blockIdx.y;
  const int c4 = threadIdx.x * 4;
  const float* base = e + (size_t)bz * 1048576 + (size_t)ry * 256 * 1024 + c4;
  float m[4] = {-3.0e38f, -3.0e38f, -3.0e38f, -3.0e38f};
  float s[4] = {0.f, 0.f, 0.f, 0.f};
#pragma unroll 4
  for (int r = 0; r < 256; ++r) {
    float4 v = *(const float4*)(base + (size_t)r * 1024);
    float vv[4] = {v.x, v.y, v.z, v.w};
#pragma unroll
    for (int j = 0; j < 4; ++j) {
      float nm = fmaxf(m[j], vv[j]);
      s[j] = s[j] * exp2f((m[j] - nm) * L2E) + exp2f((vv[j] - nm) * L2E);
      m[j] = nm;
    }
  }
  const size_t o = (size_t)(ry * 16 + bz) * 1024 + c4;
  *(float4*)(pm + o) = make_float4(m[0], m[1], m[2], m[3]);
  *(float4*)(ps + o) = make_float4(s[0], s[1], s[2], s[3]);
}

__global__ __launch_bounds__(256)
void col_combine(const float* __restrict__ pm, const float* __restrict__ ps,
                 float* __restrict__ cmax, float* __restrict__ cinv)
{
  const int bz = blockIdx.x;
  const int c4 = threadIdx.x * 4;
  float m[4] = {-3.0e38f, -3.0e38f, -3.0e38f, -3.0e38f};
  float s[4] = {0.f, 0.f, 0.f, 0.f};
#pragma unroll
  for (int ry = 0; ry < 4; ++ry) {
    const size_t o = (size_t)(ry * 16 + bz) * 1024 + c4;
    float4 vm = *(const float4*)(pm + o);
    float4 vs = *(const float4*)(ps + o);
    float mm[4] = {vm.x, vm.y, vm.z, vm.w};
    float ss[4] = {vs.x, vs.y, vs.z, vs.w};
#pragma unroll
    for (int j = 0; j < 4; ++j) {
      float nm = fmaxf(m[j], mm[j]);
      s[j] = s[j] * exp2f((m[j] - nm) * L2E) + ss[j] * exp2f((mm[j] - nm) * L2E);
      m[j] = nm;
    }
  }
  const size_t o = (size_t)bz * 1024 + c4;
  *(float4*)(cmax + o) = make_float4(m[0], m[1], m[2], m[3]);
  *(float4*)(cinv + o) = make_float4(1.f / s[0], 1.f / s[1], 1.f / s[2], 1.f / s[3]);
}

// read e 64x64 tile once; write P (row-softmax, f16 row-major) and
// PT (col-softmax, f16, transposed) via LDS tile.
__global__ __launch_bounds__(256)
void softmax_apply(const float* __restrict__ e,
                   const float* __restrict__ rm, const float* __restrict__ ri,
                   const float* __restrict__ cm, const float* __restrict__ ci,
                   _Float16* __restrict__ P, _Float16* __restrict__ PT)
{
  __shared__ _Float16 tl[64][65];
  const int bz = blockIdx.z;
  const int r0 = blockIdx.y * 64, c0 = blockIdx.x * 64;
  const size_t bo = (size_t)bz * 1048576;
  const int t = threadIdx.x;
#pragma unroll
  for (int p = 0; p < 4; ++p) {
    int idx = p * 256 + t;
    int row = idx >> 4, col4 = (idx & 15) * 4;
    float4 v = *(const float4*)(e + bo + (size_t)(r0 + row) * 1024 + c0 + col4);
    float vv[4] = {v.x, v.y, v.z, v.w};
    const float mrow = rm[bz * 1024 + r0 + row];
    const float irow = ri[bz * 1024 + r0 + row];
    half4v op;
#pragma unroll
    for (int j = 0; j < 4; ++j) {
      op[j] = (_Float16)(exp2f((vv[j] - mrow) * L2E) * irow);
      float mcol = cm[bz * 1024 + c0 + col4 + j];
      float icol = ci[bz * 1024 + c0 + col4 + j];
      tl[col4 + j][row] = (_Float16)(exp2f((vv[j] - mcol) * L2E) * icol);
    }
    *(half4v*)(P + bo + (size_t)(r0 + row) * 1024 + c0 + col4) = op;
  }
  __syncthreads();
#pragma unroll
  for (int p = 0; p < 4; ++p) {
    int idx = p * 256 + t;
    int trow = idx >> 4, tcol4 = (idx & 15) * 4;
    half4v ov;
#pragma unroll
    for (int j = 0; j < 4; ++j) ov[j] = tl[trow][tcol4 + j];
    *(half4v*)(PT + bo + (size_t)(c0 + trow) * 1024 + r0 + tcol4) = ov;
  }
}

// fp32 (R,C) -> f16 (C,R), batched via blockIdx.z (stride R*C both sides)
__global__ __launch_bounds__(256)
void transpose_cvt(const float* __restrict__ in, _Float16* __restrict__ out, int R, int C)
{
  __shared__ float tl[32][33];
  const size_t bo = (size_t)blockIdx.z * R * C;
  int x = blockIdx.x * 32 + threadIdx.x;
  int y0 = blockIdx.y * 32;
  for (int i = threadIdx.y; i < 32; i += 8)
    tl[i][threadIdx.x] = in[bo + (size_t)(y0 + i) * C + x];
  __syncthreads();
  int xo = y0 + threadIdx.x;
  int c0 = blockIdx.x * 32;
  for (int i = threadIdx.y; i < 32; i += 8)
    out[bo + (size_t)(c0 + i) * R + xo] = (_Float16)tl[threadIdx.x][i];
}

__global__ __launch_bounds__(256)
void cvt_f16(const float* __restrict__ in, _Float16* __restrict__ out, int n4)
{
  int i = blockIdx.x * 256 + threadIdx.x;
  if (i >= n4) return;
  float4 v = ((const float4*)in)[i];
  half4v o;
  o[0] = (_Float16)v.x; o[1] = (_Float16)v.y; o[2] = (_Float16)v.z; o[3] = (_Float16)v.w;
  ((half4v*)out)[i] = o;
}

extern "C" void kernel_launch(void* const* d_in, const int* in_sizes, int n_in,
                              void* d_out, int out_size, void* d_ws, size_t ws_size,
                              hipStream_t stream)
{
  const float* A  = (const float*)d_in[0];
  const float* B  = (const float*)d_in[1];
  const float* W1 = (const float*)d_in[2];
  const float* b1 = (const float*)d_in[3];
  const float* W2 = (const float*)d_in[4];
  const float* b2 = (const float*)d_in[5];
  float* out = (float*)d_out;

  char* ws = (char*)d_ws;
  _Float16* Af  = (_Float16*)(ws + 0);           // X = Af||Bf = (32768,768)
  _Float16* Bf  = (_Float16*)(ws + 25165824);
  _Float16* W1t = (_Float16*)(ws + 50331648);
  _Float16* W2t = (_Float16*)(ws + 51904512);
  float*    pm  = (float*)   (ws + 50331648);    // alias W1t/W2t (dead by then)
  float*    ps  = (float*)   (ws + 50331648 + 262144);
  _Float16* fAB = (_Float16*)(ws + 54001664);    // (32768,1024); fA first 16 batches' rows
  _Float16* P   = (_Float16*)(ws + 54001664);    // alias fAB (dead after e-gemm)
  _Float16* PT  = (_Float16*)(ws + 87556096);
  _Float16* h   = (_Float16*)(ws + 121110528);   // (32768,1024)
  float*    e   = (float*)   (ws + 121110528);   // alias h (dead after gemm2)
  float*    me  = (float*)   (ws + 188219392);
  float*    ie  = (float*)   (ws + 188219392 + 65536);
  float*    mc  = (float*)   (ws + 188219392 + 131072);
  float*    ic  = (float*)   (ws + 188219392 + 196608);
  _Float16* fA = fAB;
  _Float16* fB = fAB + 16777216;
  _Float16* At = Af;
  _Float16* Bt = Bf;

  dim3 blk(256);
  dim3 tblk(32, 8);

  cvt_f16<<<12288, blk, 0, stream>>>(A, Af, 3145728);
  cvt_f16<<<12288, blk, 0, stream>>>(B, Bf, 3145728);
  transpose_cvt<<<dim3(32, 24, 1), tblk, 0, stream>>>(W1, W1t, 768, 1024);
  transpose_cvt<<<dim3(32, 32, 1), tblk, 0, stream>>>(W2, W2t, 1024, 1024);

  // h = relu([Af;Bf] @ W1 + b1)   (32768 x 1024)
  gemm_k<768, true, _Float16><<<dim3(8, 256, 1), blk, 0, stream>>>(
      Af, W1t, b1, h, 1024, 0, 0, 0);
  // At/Bt (f16 (768,1024) per batch) — Af/Bf dead after gemm1
  transpose_cvt<<<dim3(24, 32, 16), tblk, 0, stream>>>(A, At, 1024, 768);
  transpose_cvt<<<dim3(24, 32, 16), tblk, 0, stream>>>(B, Bt, 1024, 768);
  // fAB = relu(h @ W2 + b2)
  gemm_k<1024, true, _Float16><<<dim3(8, 256, 1), blk, 0, stream>>>(
      h, W2t, b2, fAB, 1024, 0, 0, 0);

  // e = fA @ fB^T  (batched, fp32 out; h dead)
  gemm_k<1024, false, float><<<dim3(8, 8, 16), blk, 0, stream>>>(
      fA, fB, nullptr, e, 1024, 1048576L, 1048576L, 1048576L);

  row_stats<<<4096, blk, 0, stream>>>(e, me, ie);
  col_partial<<<dim3(4, 16), blk, 0, stream>>>(e, pm, ps);
  col_combine<<<16, blk, 0, stream>>>(pm, ps, mc, ic);

  softmax_apply<<<dim3(16, 16, 16), blk, 0, stream>>>(e, me, ie, mc, ic, P, PT);

  // beta = P @ Bt   -> out[0 : 12582912]
  gemm_k<1024, false, float><<<dim3(6, 8, 16), blk, 0, stream>>>(
      P, Bt, nullptr, out, 768, 1048576L, 786432L, 786432L);
  // alpha = PT @ At -> out[12582912 : ]
  gemm_k<1024, false, float><<<dim3(6, 8, 16), blk, 0, stream>>>(
      PT, At, nullptr, out + 12582912, 768, 1048576L, 786432L, 786432L);
}

// Round 4
// 540.000 us; speedup vs baseline: 1.2462x; 1.2015x over previous
//
#include <hip/hip_runtime.h>
#include <cstdint>

// R4: XCD-aware swizzled 1D grid for all gemms (id%8 -> XCD; each XCD owns an
// m-strip / batch pair so its L2 holds the shared A-tiles). e-gemm epilogue
// computes row/col softmax partials (max,sum) via shuffle+LDS reduction;
// a tiny combine kernel finishes the stats. row_stats/col_partial removed.

#define L2E 1.4426950408889634f

typedef _Float16 half8 __attribute__((ext_vector_type(8)));
typedef _Float16 half4v __attribute__((ext_vector_type(4)));
typedef float f32x4 __attribute__((ext_vector_type(4)));

__device__ __forceinline__ void gl_lds16(const void* g, void* l) {
  __builtin_amdgcn_global_load_lds(
      (const __attribute__((address_space(1))) unsigned int*)g,
      (__attribute__((address_space(3))) unsigned int*)l, 16, 0, 0);
}

// C(M,N) = op( X(M,K) @ Y(N,K)^T + bias ), op = relu if BIASRELU.
// 1D grid, XCD swizzle: c=id&7 owns m-strip (gz==1) or gz/8 batches.
// STATS: also emit per-block row/col online-softmax partials (for e).
template<int K, bool BIASRELU, bool STATS, typename OutT>
__global__ __launch_bounds__(256, 2)
void gemm_k(const _Float16* __restrict__ X, const _Float16* __restrict__ Y,
            const float* __restrict__ bias, OutT* __restrict__ C, int N,
            long xbs, long ybs, long cbs, int gm, int gn, int gz,
            float* __restrict__ prm, float* __restrict__ prs,
            float* __restrict__ pcm, float* __restrict__ pcs)
{
  __shared__ __align__(16) _Float16 sA[128 * 32];
  __shared__ __align__(16) _Float16 sB[128 * 32];
  const int t = threadIdx.x;
  const int lane = t & 63, w = t >> 6;
  const int wr = w >> 1, wc = w & 1;
  const int lm = lane & 15, lk = (lane >> 4) * 8;

  // swizzle decode
  const int id = blockIdx.x;
  const int c = id & 7, s = id >> 3;
  int m, n, bz;
  if (gz == 1) {
    int q = s / gn;
    n = s - q * gn;
    m = c * (gm >> 3) + q;
    bz = 0;
  } else {
    int tpb = gm * gn;
    int bq = s / tpb;
    bz = c * (gz >> 3) + bq;
    int r = s - bq * tpb;
    int mq = r / gn;
    m = mq;
    n = r - mq * gn;
  }
  const int m0 = m * 128, n0 = n * 128;

  X += (size_t)bz * xbs;
  Y += (size_t)bz * ybs;
  C += (size_t)bz * cbs;

  f32x4 acc[4][4] = {};

  for (int kt = 0; kt < K; kt += 32) {
    __syncthreads();
#pragma unroll
    for (int r = 0; r < 2; ++r) {
      int cid = r * 256 + t;
      int row = cid >> 2, c8 = (cid & 3) * 8;
      gl_lds16(X + (size_t)(m0 + row) * K + kt + c8, sA + cid * 8);
    }
#pragma unroll
    for (int r = 0; r < 2; ++r) {
      int cid = r * 256 + t;
      int row = cid >> 2, c8 = (cid & 3) * 8;
      gl_lds16(Y + (size_t)(n0 + row) * K + kt + c8, sB + cid * 8);
    }
    __syncthreads();

    half8 af[4], bf[4];
#pragma unroll
    for (int mi = 0; mi < 4; ++mi)
      af[mi] = *(const half8*)(sA + (wr * 64 + mi * 16 + lm) * 32 + lk);
#pragma unroll
    for (int ni = 0; ni < 4; ++ni)
      bf[ni] = *(const half8*)(sB + (wc * 64 + ni * 16 + lm) * 32 + lk);
#pragma unroll
    for (int mi = 0; mi < 4; ++mi)
#pragma unroll
      for (int ni = 0; ni < 4; ++ni)
        acc[mi][ni] = __builtin_amdgcn_mfma_f32_16x16x32_f16(af[mi], bf[ni], acc[mi][ni], 0, 0, 0);
  }

#pragma unroll
  for (int mi = 0; mi < 4; ++mi) {
    const int rbase = m0 + wr * 64 + mi * 16 + (lane >> 4) * 4;
#pragma unroll
    for (int ni = 0; ni < 4; ++ni) {
      const int col = n0 + wc * 64 + ni * 16 + lm;
      float bv = 0.f;
      if constexpr (BIASRELU) bv = bias[col];
#pragma unroll
      for (int q = 0; q < 4; ++q) {
        float v = acc[mi][ni][q] + bv;
        if constexpr (BIASRELU) v = fmaxf(v, 0.f);
        C[(size_t)(rbase + q) * N + col] = (OutT)v;
      }
    }
  }

  if constexpr (STATS) {
    __shared__ float sRm[256], sRs[256], sCm[256], sCs[256];
    // --- row partials: wave (wr,wc) covers rows wr*64..+63 x cols wc*64..+63
    float rowm[4][4], rows_[4][4];
#pragma unroll
    for (int mi = 0; mi < 4; ++mi) {
#pragma unroll
      for (int q = 0; q < 4; ++q) {
        float mloc = fmaxf(fmaxf(acc[mi][0][q], acc[mi][1][q]),
                           fmaxf(acc[mi][2][q], acc[mi][3][q]));
#pragma unroll
        for (int msk = 1; msk < 16; msk <<= 1)
          mloc = fmaxf(mloc, __shfl_xor(mloc, msk));
        float sl = 0.f;
#pragma unroll
        for (int ni = 0; ni < 4; ++ni)
          sl += exp2f((acc[mi][ni][q] - mloc) * L2E);
#pragma unroll
        for (int msk = 1; msk < 16; msk <<= 1)
          sl += __shfl_xor(sl, msk);
        rowm[mi][q] = mloc;
        rows_[mi][q] = sl;
      }
    }
    if (lm == 0) {
#pragma unroll
      for (int mi = 0; mi < 4; ++mi)
#pragma unroll
        for (int q = 0; q < 4; ++q) {
          int rloc = wr * 64 + mi * 16 + (lane >> 4) * 4 + q;
          sRm[wc * 128 + rloc] = rowm[mi][q];
          sRs[wc * 128 + rloc] = rows_[mi][q];
        }
    }
    // --- col partials: col = n0 + wc*64 + ni*16 + lm, over rows of wr-half
#pragma unroll
    for (int ni = 0; ni < 4; ++ni) {
      float mloc = -3.0e38f;
#pragma unroll
      for (int mi = 0; mi < 4; ++mi)
#pragma unroll
        for (int q = 0; q < 4; ++q)
          mloc = fmaxf(mloc, acc[mi][ni][q]);
      mloc = fmaxf(mloc, __shfl_xor(mloc, 16));
      mloc = fmaxf(mloc, __shfl_xor(mloc, 32));
      float sl = 0.f;
#pragma unroll
      for (int mi = 0; mi < 4; ++mi)
#pragma unroll
        for (int q = 0; q < 4; ++q)
          sl += exp2f((acc[mi][ni][q] - mloc) * L2E);
      sl += __shfl_xor(sl, 16);
      sl += __shfl_xor(sl, 32);
      if ((lane >> 4) == 0) {
        int cloc = wc * 64 + ni * 16 + lm;
        sCm[wr * 128 + cloc] = mloc;
        sCs[wr * 128 + cloc] = sl;
      }
    }
    __syncthreads();
    if (t < 128) {
      float m1 = sRm[t], m2 = sRm[128 + t];
      float M = fmaxf(m1, m2);
      float S = sRs[t] * exp2f((m1 - M) * L2E) + sRs[128 + t] * exp2f((m2 - M) * L2E);
      size_t o = ((size_t)bz * 8 + n) * 1024 + m0 + t;
      prm[o] = M;
      prs[o] = S;
    } else {
      int u = t - 128;
      float m1 = sCm[u], m2 = sCm[128 + u];
      float M = fmaxf(m1, m2);
      float S = sCs[u] * exp2f((m1 - M) * L2E) + sCs[128 + u] * exp2f((m2 - M) * L2E);
      size_t o = ((size_t)bz * 8 + m) * 1024 + n0 + u;
      pcm[o] = M;
      pcs[o] = S;
    }
  }
}

// combine 8 partial (max,sum) chunks -> final max and 1/sum.
// grid (64, 2): y=0 rows -> rm/ri, y=1 cols -> cm/ci
__global__ __launch_bounds__(256)
void stats_combine(const float* __restrict__ prm, const float* __restrict__ prs,
                   const float* __restrict__ pcm, const float* __restrict__ pcs,
                   float* __restrict__ rm, float* __restrict__ ri,
                   float* __restrict__ cm, float* __restrict__ ci)
{
  int idx = blockIdx.x * 256 + threadIdx.x;  // bz*1024 + pos
  int bz = idx >> 10, pos = idx & 1023;
  const float* pm = blockIdx.y ? pcm : prm;
  const float* ps = blockIdx.y ? pcs : prs;
  float mj[8], sj[8];
#pragma unroll
  for (int j = 0; j < 8; ++j) {
    size_t o = ((size_t)bz * 8 + j) * 1024 + pos;
    mj[j] = pm[o];
    sj[j] = ps[o];
  }
  float M = -3.0e38f;
#pragma unroll
  for (int j = 0; j < 8; ++j) M = fmaxf(M, mj[j]);
  float S = 0.f;
#pragma unroll
  for (int j = 0; j < 8; ++j) S += sj[j] * exp2f((mj[j] - M) * L2E);
  float* om = blockIdx.y ? cm : rm;
  float* oi = blockIdx.y ? ci : ri;
  om[idx] = M;
  oi[idx] = 1.f / S;
}

// read e 64x64 tile once; write P (row-softmax, f16) and PT (col-softmax, transposed)
__global__ __launch_bounds__(256)
void softmax_apply(const float* __restrict__ e,
                   const float* __restrict__ rm, const float* __restrict__ ri,
                   const float* __restrict__ cm, const float* __restrict__ ci,
                   _Float16* __restrict__ P, _Float16* __restrict__ PT)
{
  __shared__ _Float16 tl[64][65];
  const int bz = blockIdx.z;
  const int r0 = blockIdx.y * 64, c0 = blockIdx.x * 64;
  const size_t bo = (size_t)bz * 1048576;
  const int t = threadIdx.x;
#pragma unroll
  for (int p = 0; p < 4; ++p) {
    int idx = p * 256 + t;
    int row = idx >> 4, col4 = (idx & 15) * 4;
    float4 v = *(const float4*)(e + bo + (size_t)(r0 + row) * 1024 + c0 + col4);
    float vv[4] = {v.x, v.y, v.z, v.w};
    const float mrow = rm[bz * 1024 + r0 + row];
    const float irow = ri[bz * 1024 + r0 + row];
    half4v op;
#pragma unroll
    for (int j = 0; j < 4; ++j) {
      op[j] = (_Float16)(exp2f((vv[j] - mrow) * L2E) * irow);
      float mcol = cm[bz * 1024 + c0 + col4 + j];
      float icol = ci[bz * 1024 + c0 + col4 + j];
      tl[col4 + j][row] = (_Float16)(exp2f((vv[j] - mcol) * L2E) * icol);
    }
    *(half4v*)(P + bo + (size_t)(r0 + row) * 1024 + c0 + col4) = op;
  }
  __syncthreads();
#pragma unroll
  for (int p = 0; p < 4; ++p) {
    int idx = p * 256 + t;
    int trow = idx >> 4, tcol4 = (idx & 15) * 4;
    half4v ov;
#pragma unroll
    for (int j = 0; j < 4; ++j) ov[j] = tl[trow][tcol4 + j];
    *(half4v*)(PT + bo + (size_t)(c0 + trow) * 1024 + r0 + tcol4) = ov;
  }
}

// fp32 (R,C) -> f16 (C,R), batched via blockIdx.z
__global__ __launch_bounds__(256)
void transpose_cvt(const float* __restrict__ in, _Float16* __restrict__ out, int R, int C)
{
  __shared__ float tl[32][33];
  const size_t bo = (size_t)blockIdx.z * R * C;
  int x = blockIdx.x * 32 + threadIdx.x;
  int y0 = blockIdx.y * 32;
  for (int i = threadIdx.y; i < 32; i += 8)
    tl[i][threadIdx.x] = in[bo + (size_t)(y0 + i) * C + x];
  __syncthreads();
  int xo = y0 + threadIdx.x;
  int c0 = blockIdx.x * 32;
  for (int i = threadIdx.y; i < 32; i += 8)
    out[bo + (size_t)(c0 + i) * R + xo] = (_Float16)tl[threadIdx.x][i];
}

__global__ __launch_bounds__(256)
void cvt_f16(const float* __restrict__ in, _Float16* __restrict__ out, int n4)
{
  int i = blockIdx.x * 256 + threadIdx.x;
  if (i >= n4) return;
  float4 v = ((const float4*)in)[i];
  half4v o;
  o[0] = (_Float16)v.x; o[1] = (_Float16)v.y; o[2] = (_Float16)v.z; o[3] = (_Float16)v.w;
  ((half4v*)out)[i] = o;
}

extern "C" void kernel_launch(void* const* d_in, const int* in_sizes, int n_in,
                              void* d_out, int out_size, void* d_ws, size_t ws_size,
                              hipStream_t stream)
{
  const float* A  = (const float*)d_in[0];
  const float* B  = (const float*)d_in[1];
  const float* W1 = (const float*)d_in[2];
  const float* b1 = (const float*)d_in[3];
  const float* W2 = (const float*)d_in[4];
  const float* b2 = (const float*)d_in[5];
  float* out = (float*)d_out;

  char* ws = (char*)d_ws;
  _Float16* Af  = (_Float16*)(ws + 0);           // X = Af||Bf = (32768,768)
  _Float16* Bf  = (_Float16*)(ws + 25165824);
  _Float16* W1t = (_Float16*)(ws + 50331648);
  _Float16* W2t = (_Float16*)(ws + 51904512);
  // partials overwrite W1t/W2t (dead after gemm2; e-gemm runs later)
  float*    prm = (float*)   (ws + 50331648);                 // 512KB
  float*    prs = (float*)   (ws + 50331648 + 524288);
  float*    pcm = (float*)   (ws + 50331648 + 1048576);
  float*    pcs = (float*)   (ws + 50331648 + 1572864);       // ends 52428800
  _Float16* fAB = (_Float16*)(ws + 54001664);    // (32768,1024)
  _Float16* P   = (_Float16*)(ws + 54001664);    // alias fAB (dead after e-gemm)
  _Float16* PT  = (_Float16*)(ws + 87556096);
  _Float16* h   = (_Float16*)(ws + 121110528);   // (32768,1024)
  float*    e   = (float*)   (ws + 121110528);   // alias h (dead after gemm2)
  float*    me  = (float*)   (ws + 188219392);
  float*    ie  = (float*)   (ws + 188219392 + 65536);
  float*    mc  = (float*)   (ws + 188219392 + 131072);
  float*    ic  = (float*)   (ws + 188219392 + 196608);
  _Float16* fA = fAB;
  _Float16* fB = fAB + 16777216;
  _Float16* At = Af;
  _Float16* Bt = Bf;

  dim3 blk(256);
  dim3 tblk(32, 8);

  cvt_f16<<<12288, blk, 0, stream>>>(A, Af, 3145728);
  cvt_f16<<<12288, blk, 0, stream>>>(B, Bf, 3145728);
  transpose_cvt<<<dim3(32, 24, 1), tblk, 0, stream>>>(W1, W1t, 768, 1024);
  transpose_cvt<<<dim3(32, 32, 1), tblk, 0, stream>>>(W2, W2t, 1024, 1024);

  // h = relu([Af;Bf] @ W1 + b1)   (32768 x 1024), gm=256 gn=8
  gemm_k<768, true, false, _Float16><<<2048, blk, 0, stream>>>(
      Af, W1t, b1, h, 1024, 0, 0, 0, 256, 8, 1,
      nullptr, nullptr, nullptr, nullptr);
  // At/Bt (f16 (768,1024) per batch) — Af/Bf dead after gemm1
  transpose_cvt<<<dim3(24, 32, 16), tblk, 0, stream>>>(A, At, 1024, 768);
  transpose_cvt<<<dim3(24, 32, 16), tblk, 0, stream>>>(B, Bt, 1024, 768);
  // fAB = relu(h @ W2 + b2)
  gemm_k<1024, true, false, _Float16><<<2048, blk, 0, stream>>>(
      h, W2t, b2, fAB, 1024, 0, 0, 0, 256, 8, 1,
      nullptr, nullptr, nullptr, nullptr);

  // e = fA @ fB^T (batched fp32) + softmax partials in epilogue
  gemm_k<1024, false, true, float><<<1024, blk, 0, stream>>>(
      fA, fB, nullptr, e, 1024, 1048576L, 1048576L, 1048576L, 8, 8, 16,
      prm, prs, pcm, pcs);

  stats_combine<<<dim3(64, 2), blk, 0, stream>>>(prm, prs, pcm, pcs, me, ie, mc, ic);

  softmax_apply<<<dim3(16, 16, 16), blk, 0, stream>>>(e, me, ie, mc, ic, P, PT);

  // beta = P @ Bt   -> out[0 : 12582912]    gm=8 gn=6 gz=16
  gemm_k<1024, false, false, float><<<768, blk, 0, stream>>>(
      P, Bt, nullptr, out, 768, 1048576L, 786432L, 786432L, 8, 6, 16,
      nullptr, nullptr, nullptr, nullptr);
  // alpha = PT @ At -> out[12582912 : ]
  gemm_k<1024, false, false, float><<<768, blk, 0, stream>>>(
      PT, At, nullptr, out + 12582912, 768, 1048576L, 786432L, 786432L, 8, 6, 16,
      nullptr, nullptr, nullptr, nullptr);
}

// Round 5
// 502.414 us; speedup vs baseline: 1.3394x; 1.0748x over previous
//
#include <hip/hip_runtime.h>
#include <cstdint>

// R5: (a) XOR-swizzled LDS chunk layout kills the 8-way bank conflict on
// fragment ds_read_b128 while keeping global_load_lds DMA staging (row r's
// k-chunk c stored at position c^(r&7); read quad = (kc^(lm&7))%8 -> 2-way,
// free). (b) BK=64 halves barrier count (short-K gemms were drain-bound).
// (c) launch merges: beta+alpha one launch, stats-combine inlined into
// softmax_apply, cvt A/B merged, At/Bt transposes merged.

#define L2E 1.4426950408889634f

typedef _Float16 half8 __attribute__((ext_vector_type(8)));
typedef _Float16 half4v __attribute__((ext_vector_type(4)));
typedef float f32x4 __attribute__((ext_vector_type(4)));

__device__ __forceinline__ void gl_lds16(const void* g, void* l) {
  __builtin_amdgcn_global_load_lds(
      (const __attribute__((address_space(1))) unsigned int*)g,
      (__attribute__((address_space(3))) unsigned int*)l, 16, 0, 0);
}

// C(M,N) = op( X(M,K) @ Y(N,K)^T + bias ), op = relu if BIASRELU.
// 1D grid + XCD swizzle (id&7 -> XCD). shalf>0: merged two-gemm launch
// (s >= shalf uses X2/Y2/C2). STATS: emit row/col softmax partials.
template<int K, bool BIASRELU, bool STATS, typename OutT>
__global__ __launch_bounds__(256, 2)
void gemm_k(const _Float16* __restrict__ X, const _Float16* __restrict__ Y,
            const float* __restrict__ bias, OutT* __restrict__ C, int N,
            long xbs, long ybs, long cbs, int gm, int gn, int gz,
            float* __restrict__ prm, float* __restrict__ prs,
            float* __restrict__ pcm, float* __restrict__ pcs,
            const _Float16* __restrict__ X2, const _Float16* __restrict__ Y2,
            OutT* __restrict__ C2, int shalf)
{
  __shared__ __align__(16) _Float16 sA[128 * 64];
  __shared__ __align__(16) _Float16 sB[128 * 64];
  const int t = threadIdx.x;
  const int lane = t & 63, w = t >> 6;
  const int wr = w >> 1, wc = w & 1;
  const int lm = lane & 15, g = lane >> 4;
  const int xr = lane & 7;  // == (fragment row) & 7

  // swizzle decode
  const int id = blockIdx.x;
  const int c = id & 7;
  int s = id >> 3;
  if (shalf && s >= shalf) { s -= shalf; X = X2; Y = Y2; C = C2; }
  int m, n, bz;
  if (gz == 1) {
    int q = s / gn;
    n = s - q * gn;
    m = c * (gm >> 3) + q;
    bz = 0;
  } else {
    int tpb = gm * gn;
    int bq = s / tpb;
    bz = c * (gz >> 3) + bq;
    int r = s - bq * tpb;
    m = r / gn;
    n = r - m * gn;
  }
  const int m0 = m * 128, n0 = n * 128;

  X += (size_t)bz * xbs;
  Y += (size_t)bz * ybs;
  C += (size_t)bz * cbs;

  // staging constants: chunk cid = r*256+t -> LDS row = r*32 + (t>>3),
  // pos = t&7; global k-offset = (pos ^ (row&7))*8  (row&7 == (t>>3)&7)
  const int stg_row = t >> 3;
  const int stg_koff = (((t & 7) ^ ((t >> 3) & 7)) << 3);

  // fragment LDS bases (f16 units): row*64 + ((ks*4+g)^xr)*8
  int arow[4], brow[4], axo[2];
#pragma unroll
  for (int i = 0; i < 4; ++i) {
    arow[i] = (wr * 64 + i * 16 + lm) * 64;
    brow[i] = (wc * 64 + i * 16 + lm) * 64;
  }
  axo[0] = ((0 * 4 + g) ^ xr) * 8;
  axo[1] = ((1 * 4 + g) ^ xr) * 8;

  f32x4 acc[4][4] = {};

  for (int kt = 0; kt < K; kt += 64) {
    __syncthreads();
#pragma unroll
    for (int r = 0; r < 4; ++r) {
      int row = r * 32 + stg_row;
      gl_lds16(X + (size_t)(m0 + row) * K + kt + stg_koff, sA + (r * 256 + t) * 8);
    }
#pragma unroll
    for (int r = 0; r < 4; ++r) {
      int row = r * 32 + stg_row;
      gl_lds16(Y + (size_t)(n0 + row) * K + kt + stg_koff, sB + (r * 256 + t) * 8);
    }
    __syncthreads();

    half8 af[4], bf[4];
#pragma unroll
    for (int ks = 0; ks < 2; ++ks) {
#pragma unroll
      for (int mi = 0; mi < 4; ++mi)
        af[mi] = *(const half8*)(sA + arow[mi] + axo[ks]);
#pragma unroll
      for (int ni = 0; ni < 4; ++ni)
        bf[ni] = *(const half8*)(sB + brow[ni] + axo[ks]);
#pragma unroll
      for (int mi = 0; mi < 4; ++mi)
#pragma unroll
        for (int ni = 0; ni < 4; ++ni)
          acc[mi][ni] = __builtin_amdgcn_mfma_f32_16x16x32_f16(af[mi], bf[ni], acc[mi][ni], 0, 0, 0);
    }
  }

#pragma unroll
  for (int mi = 0; mi < 4; ++mi) {
    const int rbase = m0 + wr * 64 + mi * 16 + (lane >> 4) * 4;
#pragma unroll
    for (int ni = 0; ni < 4; ++ni) {
      const int col = n0 + wc * 64 + ni * 16 + lm;
      float bv = 0.f;
      if constexpr (BIASRELU) bv = bias[col];
#pragma unroll
      for (int q = 0; q < 4; ++q) {
        float v = acc[mi][ni][q] + bv;
        if constexpr (BIASRELU) v = fmaxf(v, 0.f);
        C[(size_t)(rbase + q) * N + col] = (OutT)v;
      }
    }
  }

  if constexpr (STATS) {
    __shared__ float sRm[256], sRs[256], sCm[256], sCs[256];
    float rowm[4][4], rows_[4][4];
#pragma unroll
    for (int mi = 0; mi < 4; ++mi) {
#pragma unroll
      for (int q = 0; q < 4; ++q) {
        float mloc = fmaxf(fmaxf(acc[mi][0][q], acc[mi][1][q]),
                           fmaxf(acc[mi][2][q], acc[mi][3][q]));
#pragma unroll
        for (int msk = 1; msk < 16; msk <<= 1)
          mloc = fmaxf(mloc, __shfl_xor(mloc, msk));
        float sl = 0.f;
#pragma unroll
        for (int ni = 0; ni < 4; ++ni)
          sl += exp2f((acc[mi][ni][q] - mloc) * L2E);
#pragma unroll
        for (int msk = 1; msk < 16; msk <<= 1)
          sl += __shfl_xor(sl, msk);
        rowm[mi][q] = mloc;
        rows_[mi][q] = sl;
      }
    }
    if (lm == 0) {
#pragma unroll
      for (int mi = 0; mi < 4; ++mi)
#pragma unroll
        for (int q = 0; q < 4; ++q) {
          int rloc = wr * 64 + mi * 16 + (lane >> 4) * 4 + q;
          sRm[wc * 128 + rloc] = rowm[mi][q];
          sRs[wc * 128 + rloc] = rows_[mi][q];
        }
    }
#pragma unroll
    for (int ni = 0; ni < 4; ++ni) {
      float mloc = -3.0e38f;
#pragma unroll
      for (int mi = 0; mi < 4; ++mi)
#pragma unroll
        for (int q = 0; q < 4; ++q)
          mloc = fmaxf(mloc, acc[mi][ni][q]);
      mloc = fmaxf(mloc, __shfl_xor(mloc, 16));
      mloc = fmaxf(mloc, __shfl_xor(mloc, 32));
      float sl = 0.f;
#pragma unroll
      for (int mi = 0; mi < 4; ++mi)
#pragma unroll
        for (int q = 0; q < 4; ++q)
          sl += exp2f((acc[mi][ni][q] - mloc) * L2E);
      sl += __shfl_xor(sl, 16);
      sl += __shfl_xor(sl, 32);
      if ((lane >> 4) == 0) {
        int cloc = wc * 64 + ni * 16 + lm;
        sCm[wr * 128 + cloc] = mloc;
        sCs[wr * 128 + cloc] = sl;
      }
    }
    __syncthreads();
    if (t < 128) {
      float m1 = sRm[t], m2 = sRm[128 + t];
      float M = fmaxf(m1, m2);
      float S = sRs[t] * exp2f((m1 - M) * L2E) + sRs[128 + t] * exp2f((m2 - M) * L2E);
      size_t o = ((size_t)bz * 8 + n) * 1024 + m0 + t;
      prm[o] = M;
      prs[o] = S;
    } else {
      int u = t - 128;
      float m1 = sCm[u], m2 = sCm[128 + u];
      float M = fmaxf(m1, m2);
      float S = sCs[u] * exp2f((m1 - M) * L2E) + sCs[128 + u] * exp2f((m2 - M) * L2E);
      size_t o = ((size_t)bz * 8 + m) * 1024 + n0 + u;
      pcm[o] = M;
      pcs[o] = S;
    }
  }
}

// read e 64x64 tile once; combine partial stats inline; write P (row-softmax)
// and PT (col-softmax, transposed via LDS)
__global__ __launch_bounds__(256)
void softmax_apply(const float* __restrict__ e,
                   const float* __restrict__ prm, const float* __restrict__ prs,
                   const float* __restrict__ pcm, const float* __restrict__ pcs,
                   _Float16* __restrict__ P, _Float16* __restrict__ PT)
{
  __shared__ _Float16 tl[64][65];
  __shared__ float sRm[64], sRi[64], sCm[64], sCi[64];
  const int bz = blockIdx.z;
  const int r0 = blockIdx.y * 64, c0 = blockIdx.x * 64;
  const size_t bo = (size_t)bz * 1048576;
  const int t = threadIdx.x;

  if (t < 128) {
    const int isCol = t >> 6;
    const int u = t & 63;
    const float* pm = isCol ? pcm : prm;
    const float* ps = isCol ? pcs : prs;
    const int pos = (isCol ? c0 : r0) + u;
    float mj[8], sj[8];
#pragma unroll
    for (int j = 0; j < 8; ++j) {
      size_t o = ((size_t)bz * 8 + j) * 1024 + pos;
      mj[j] = pm[o];
      sj[j] = ps[o];
    }
    float M = -3.0e38f;
#pragma unroll
    for (int j = 0; j < 8; ++j) M = fmaxf(M, mj[j]);
    float S = 0.f;
#pragma unroll
    for (int j = 0; j < 8; ++j) S += sj[j] * exp2f((mj[j] - M) * L2E);
    if (isCol) { sCm[u] = M; sCi[u] = 1.f / S; }
    else       { sRm[u] = M; sRi[u] = 1.f / S; }
  }
  __syncthreads();

#pragma unroll
  for (int p = 0; p < 4; ++p) {
    int idx = p * 256 + t;
    int row = idx >> 4, col4 = (idx & 15) * 4;
    float4 v = *(const float4*)(e + bo + (size_t)(r0 + row) * 1024 + c0 + col4);
    float vv[4] = {v.x, v.y, v.z, v.w};
    const float mrow = sRm[row];
    const float irow = sRi[row];
    half4v op;
#pragma unroll
    for (int j = 0; j < 4; ++j) {
      op[j] = (_Float16)(exp2f((vv[j] - mrow) * L2E) * irow);
      tl[col4 + j][row] = (_Float16)(exp2f((vv[j] - sCm[col4 + j]) * L2E) * sCi[col4 + j]);
    }
    *(half4v*)(P + bo + (size_t)(r0 + row) * 1024 + c0 + col4) = op;
  }
  __syncthreads();
#pragma unroll
  for (int p = 0; p < 4; ++p) {
    int idx = p * 256 + t;
    int trow = idx >> 4, tcol4 = (idx & 15) * 4;
    half4v ov;
#pragma unroll
    for (int j = 0; j < 4; ++j) ov[j] = tl[trow][tcol4 + j];
    *(half4v*)(PT + bo + (size_t)(c0 + trow) * 1024 + r0 + tcol4) = ov;
  }
}

// fp32 (R,C) -> f16 (C,R). DUAL=false: in1 only, grid z = batches.
// DUAL=true: grid z in [0,2*NB): z<NB -> in1/out1, else in2/out2.
__global__ __launch_bounds__(256)
void transpose_cvt(const float* __restrict__ in1, _Float16* __restrict__ out1,
                   const float* __restrict__ in2, _Float16* __restrict__ out2,
                   int R, int C, int nb)
{
  __shared__ float tl[32][33];
  int z = blockIdx.z;
  const float* in = in1;
  _Float16* out = out1;
  if (z >= nb) { z -= nb; in = in2; out = out2; }
  const size_t bo = (size_t)z * R * C;
  int x = blockIdx.x * 32 + threadIdx.x;
  int y0 = blockIdx.y * 32;
  for (int i = threadIdx.y; i < 32; i += 8)
    tl[i][threadIdx.x] = in[bo + (size_t)(y0 + i) * C + x];
  __syncthreads();
  int xo = y0 + threadIdx.x;
  int c0 = blockIdx.x * 32;
  for (int i = threadIdx.y; i < 32; i += 8)
    out[bo + (size_t)(c0 + i) * R + xo] = (_Float16)tl[threadIdx.x][i];
}

__global__ __launch_bounds__(256)
void cvt_f16_2(const float* __restrict__ inA, const float* __restrict__ inB,
               _Float16* __restrict__ oA, _Float16* __restrict__ oB, int n4)
{
  int i = blockIdx.x * 256 + threadIdx.x;
  const float* in = inA;
  _Float16* out = oA;
  if (i >= n4) { i -= n4; in = inB; out = oB; }
  float4 v = ((const float4*)in)[i];
  half4v o;
  o[0] = (_Float16)v.x; o[1] = (_Float16)v.y; o[2] = (_Float16)v.z; o[3] = (_Float16)v.w;
  ((half4v*)out)[i] = o;
}

extern "C" void kernel_launch(void* const* d_in, const int* in_sizes, int n_in,
                              void* d_out, int out_size, void* d_ws, size_t ws_size,
                              hipStream_t stream)
{
  const float* A  = (const float*)d_in[0];
  const float* B  = (const float*)d_in[1];
  const float* W1 = (const float*)d_in[2];
  const float* b1 = (const float*)d_in[3];
  const float* W2 = (const float*)d_in[4];
  const float* b2 = (const float*)d_in[5];
  float* out = (float*)d_out;

  char* ws = (char*)d_ws;
  _Float16* Af  = (_Float16*)(ws + 0);           // X = Af||Bf = (32768,768)
  _Float16* Bf  = (_Float16*)(ws + 25165824);
  _Float16* W1t = (_Float16*)(ws + 50331648);
  _Float16* W2t = (_Float16*)(ws + 51904512);
  // partials overwrite W1t/W2t (dead after gemm2; e-gemm runs later)
  float*    prm = (float*)   (ws + 50331648);
  float*    prs = (float*)   (ws + 50331648 + 524288);
  float*    pcm = (float*)   (ws + 50331648 + 1048576);
  float*    pcs = (float*)   (ws + 50331648 + 1572864);
  _Float16* fAB = (_Float16*)(ws + 54001664);    // (32768,1024)
  _Float16* P   = (_Float16*)(ws + 54001664);    // alias fAB (dead after e-gemm)
  _Float16* PT  = (_Float16*)(ws + 87556096);
  _Float16* h   = (_Float16*)(ws + 121110528);   // (32768,1024)
  float*    e   = (float*)   (ws + 121110528);   // alias h (dead after gemm2)
  _Float16* fA = fAB;
  _Float16* fB = fAB + 16777216;
  _Float16* At = Af;
  _Float16* Bt = Bf;

  dim3 blk(256);
  dim3 tblk(32, 8);

  cvt_f16_2<<<24576, blk, 0, stream>>>(A, B, Af, Bf, 3145728);
  transpose_cvt<<<dim3(32, 24, 1), tblk, 0, stream>>>(W1, W1t, nullptr, nullptr, 768, 1024, 1);
  transpose_cvt<<<dim3(32, 32, 1), tblk, 0, stream>>>(W2, W2t, nullptr, nullptr, 1024, 1024, 1);

  // h = relu([Af;Bf] @ W1 + b1)  (32768x1024), gm=256 gn=8
  gemm_k<768, true, false, _Float16><<<2048, blk, 0, stream>>>(
      Af, W1t, b1, h, 1024, 0, 0, 0, 256, 8, 1,
      nullptr, nullptr, nullptr, nullptr, nullptr, nullptr, nullptr, 0);
  // At/Bt (f16 (768,1024) per batch) — Af/Bf dead after gemm1
  transpose_cvt<<<dim3(24, 32, 32), tblk, 0, stream>>>(A, At, B, Bt, 1024, 768, 16);
  // fAB = relu(h @ W2 + b2)
  gemm_k<1024, true, false, _Float16><<<2048, blk, 0, stream>>>(
      h, W2t, b2, fAB, 1024, 0, 0, 0, 256, 8, 1,
      nullptr, nullptr, nullptr, nullptr, nullptr, nullptr, nullptr, 0);

  // e = fA @ fB^T (batched fp32) + softmax partials in epilogue
  gemm_k<1024, false, true, float><<<1024, blk, 0, stream>>>(
      fA, fB, nullptr, e, 1024, 1048576L, 1048576L, 1048576L, 8, 8, 16,
      prm, prs, pcm, pcs, nullptr, nullptr, nullptr, 0);

  softmax_apply<<<dim3(16, 16, 16), blk, 0, stream>>>(e, prm, prs, pcm, pcs, P, PT);

  // beta = P @ Bt -> out[0:12582912]; alpha = PT @ At -> out[12582912:]
  // merged launch: gm=8 gn=6 gz=16 per half, shalf = 2*48 = 96
  gemm_k<1024, false, false, float><<<1536, blk, 0, stream>>>(
      P, Bt, nullptr, out, 768, 1048576L, 786432L, 786432L, 8, 6, 16,
      nullptr, nullptr, nullptr, nullptr, PT, At, out + 12582912, 96);
}